// Round 2
// baseline (35.800 us; speedup 1.0000x reference)
//
#include <hip/hip_runtime.h>
#include <cmath>

#define LLEN 131072
#define IIRL 16384
#define CHUNK 4096
#define NBLK (LLEN / CHUNK)   // 32 chunks per row
#define TPB 256
#define EPT (CHUNK / TPB)     // 16 elements per thread

__device__ __forceinline__ float powiu(float b, unsigned e) {
    float r = 1.0f;
    while (e) { if (e & 1u) r *= b; b *= b; e >>= 1; }
    return r;
}

__device__ __forceinline__ float sigmoidf(float z) {
    return 1.0f / (1.0f + expf(-z));
}

// ---------------------------------------------------------------------------
// Kernel 1: per-chunk partial env value (zero carry-in) -> P[n*NBLK + chunk]
// env[t] = a*env[t-1] + (1-a)*(ls[t] - A16K*ls[t-16384]),  ls = mean_c(x^2)
// ---------------------------------------------------------------------------
__global__ __launch_bounds__(TPB) void k_partials(
    const float* __restrict__ x, const float* __restrict__ za,
    float* __restrict__ P)
{
    const int chunk = blockIdx.x, n = blockIdx.y;
    const int tid = threadIdx.x, lane = tid & 63, wid = tid >> 6;

    const float alpha = sigmoidf(za[n]);
    const float oma   = 1.0f - alpha;
    const float A16K  = powiu(alpha, IIRL);   // underflows to 0 for realistic alpha

    const long  base = (long)n * 2 * LLEN + (long)chunk * CHUNK;
    const float* x0 = x + base;
    const float* x1 = x0 + LLEN;
    const int j0 = tid * EPT;

    float b[EPT];
    {
        const float4* p0 = reinterpret_cast<const float4*>(x0 + j0);
        const float4* p1 = reinterpret_cast<const float4*>(x1 + j0);
        #pragma unroll
        for (int q = 0; q < 4; ++q) {
            float4 a = p0[q], c = p1[q];
            b[q*4+0] = 0.5f * fmaf(a.x, a.x, c.x*c.x);
            b[q*4+1] = 0.5f * fmaf(a.y, a.y, c.y*c.y);
            b[q*4+2] = 0.5f * fmaf(a.z, a.z, c.z*c.z);
            b[q*4+3] = 0.5f * fmaf(a.w, a.w, c.w*c.w);
        }
    }
    if (A16K != 0.0f && chunk >= IIRL / CHUNK) {   // uniform branch per block
        const float4* p0 = reinterpret_cast<const float4*>(x0 + j0 - IIRL);
        const float4* p1 = reinterpret_cast<const float4*>(x1 + j0 - IIRL);
        #pragma unroll
        for (int q = 0; q < 4; ++q) {
            float4 a = p0[q], c = p1[q];
            b[q*4+0] -= A16K * 0.5f * fmaf(a.x, a.x, c.x*c.x);
            b[q*4+1] -= A16K * 0.5f * fmaf(a.y, a.y, c.y*c.y);
            b[q*4+2] -= A16K * 0.5f * fmaf(a.z, a.z, c.z*c.z);
            b[q*4+3] -= A16K * 0.5f * fmaf(a.w, a.w, c.w*c.w);
        }
    }

    // thread-serial scan of 16 elems (zero init)
    float s = 0.0f;
    #pragma unroll
    for (int i = 0; i < EPT; ++i) s = fmaf(alpha, s, oma * b[i]);

    // wave-level weighted inclusive scan (segment weight a16 = alpha^16)
    const float a16 = powiu(alpha, 16u);
    float v = s, g = a16;
    #pragma unroll
    for (int off = 1; off < 64; off <<= 1) {
        float y = __shfl_up(v, off, 64);
        if (lane >= off) v = fmaf(g, y, v);
        g *= g;
    }

    __shared__ float wtot[TPB / 64];
    if (lane == 63) wtot[wid] = v;
    __syncthreads();
    if (tid == 0) {
        const float A1024 = powiu(a16, 64u);       // alpha^1024 (per-wave span)
        float p = 0.0f;
        #pragma unroll
        for (int w = 0; w < TPB / 64; ++w) p = fmaf(A1024, p, wtot[w]);
        P[n * NBLK + chunk] = p;
    }
}

// ---------------------------------------------------------------------------
// Kernel 2: recompute scan with carry-in, apply compressor gain, write output
// ---------------------------------------------------------------------------
__global__ __launch_bounds__(TPB) void k_apply(
    const float* __restrict__ x, const float* __restrict__ za,
    const float* __restrict__ lt, const float* __restrict__ lr,
    const float* __restrict__ lk, const float* __restrict__ P,
    float* __restrict__ out)
{
    const int chunk = blockIdx.x, n = blockIdx.y;
    const int tid = threadIdx.x, lane = tid & 63, wid = tid >> 6;

    const float alpha = sigmoidf(za[n]);
    const float oma   = 1.0f - alpha;
    const float A16K  = powiu(alpha, IIRL);
    const float Tthr  = lt[n] - 6.0f;
    const float ratio = 1.0f + expf(lr[n]);
    const float knee  = expf(lk[n] - 1.0f);
    const float coef  = (1.0f / ratio - 1.0f) / knee;

    const long  base = (long)n * 2 * LLEN + (long)chunk * CHUNK;
    const float* x0 = x + base;
    const float* x1 = x0 + LLEN;
    const int j0 = tid * EPT;

    float4 xa[4], xb[4];
    float  b[EPT];
    {
        const float4* p0 = reinterpret_cast<const float4*>(x0 + j0);
        const float4* p1 = reinterpret_cast<const float4*>(x1 + j0);
        #pragma unroll
        for (int q = 0; q < 4; ++q) {
            xa[q] = p0[q]; xb[q] = p1[q];
            float4 a = xa[q], c = xb[q];
            b[q*4+0] = oma * 0.5f * fmaf(a.x, a.x, c.x*c.x);
            b[q*4+1] = oma * 0.5f * fmaf(a.y, a.y, c.y*c.y);
            b[q*4+2] = oma * 0.5f * fmaf(a.z, a.z, c.z*c.z);
            b[q*4+3] = oma * 0.5f * fmaf(a.w, a.w, c.w*c.w);
        }
    }
    if (A16K != 0.0f && chunk >= IIRL / CHUNK) {
        const float4* p0 = reinterpret_cast<const float4*>(x0 + j0 - IIRL);
        const float4* p1 = reinterpret_cast<const float4*>(x1 + j0 - IIRL);
        const float sc = oma * A16K * 0.5f;
        #pragma unroll
        for (int q = 0; q < 4; ++q) {
            float4 a = p0[q], c = p1[q];
            b[q*4+0] -= sc * fmaf(a.x, a.x, c.x*c.x);
            b[q*4+1] -= sc * fmaf(a.y, a.y, c.y*c.y);
            b[q*4+2] -= sc * fmaf(a.z, a.z, c.z*c.z);
            b[q*4+3] -= sc * fmaf(a.w, a.w, c.w*c.w);
        }
    }

    // thread partial (zero init)
    float s = 0.0f;
    #pragma unroll
    for (int i = 0; i < EPT; ++i) s = fmaf(alpha, s, b[i]);

    // wave inclusive scan
    const float a16 = powiu(alpha, 16u);
    float v = s, g = a16;
    #pragma unroll
    for (int off = 1; off < 64; off <<= 1) {
        float y = __shfl_up(v, off, 64);
        if (lane >= off) v = fmaf(g, y, v);
        g *= g;
    }
    float Ew = __shfl_up(v, 1, 64);   // exclusive within-wave
    if (lane == 0) Ew = 0.0f;

    __shared__ float wtot[TPB / 64];
    __shared__ float cblk_s;
    if (lane == 63) wtot[wid] = v;
    if (tid == 0) {
        // serial scan of predecessor chunk partials -> env[chunk_start - 1]
        const float Ac = powiu(alpha, CHUNK);
        float c = 0.0f;
        for (int k = 0; k < chunk; ++k) c = fmaf(Ac, c, P[n * NBLK + k]);
        cblk_s = c;
    }
    __syncthreads();

    const float A1024 = powiu(a16, 64u);
    float wc = 0.0f;
    for (int w = 0; w < wid; ++w) wc = fmaf(A1024, wc, wtot[w]);

    const float a16l = powiu(a16, (unsigned)lane);       // alpha^(16*lane)
    float pre_blk = fmaf(a16l, wc, Ew);                  // block-local exclusive
    const float aj0 = a16l * powiu(A1024, (unsigned)wid);// alpha^(16*tid)
    float e = fmaf(aj0, cblk_s, pre_blk);                // env[chunk_start+j0-1]

    // element-wise env + gain + output
    float4 o0[4], o1[4];
    #pragma unroll
    for (int q = 0; q < 4; ++q) {
        float* oa = reinterpret_cast<float*>(&o0[q]);
        float* ob = reinterpret_cast<float*>(&o1[q]);
        const float* ia = reinterpret_cast<const float*>(&xa[q]);
        const float* ib = reinterpret_cast<const float*>(&xb[q]);
        #pragma unroll
        for (int k = 0; k < 4; ++k) {
            e = fmaf(alpha, e, b[q*4 + k]);
            float le = logf(e + 1e-5f);
            float xk = knee * (le - Tthr);
            float sp = fmaxf(xk, 0.0f) + log1pf(expf(-fabsf(xk)));
            float gain = expf(coef * sp);
            oa[k] = gain * ia[k];
            ob[k] = gain * ib[k];
        }
    }
    {
        float4* q0 = reinterpret_cast<float4*>(out + base + j0);
        float4* q1 = reinterpret_cast<float4*>(out + base + LLEN + j0);
        #pragma unroll
        for (int q = 0; q < 4; ++q) { q0[q] = o0[q]; q1[q] = o1[q]; }
    }
}

extern "C" void kernel_launch(void* const* d_in, const int* in_sizes, int n_in,
                              void* d_out, int out_size, void* d_ws, size_t ws_size,
                              hipStream_t stream) {
    const float* x  = (const float*)d_in[0];
    const float* za = (const float*)d_in[1];
    const float* lt = (const float*)d_in[2];
    const float* lr = (const float*)d_in[3];
    const float* lk = (const float*)d_in[4];
    float* out = (float*)d_out;
    float* P   = (float*)d_ws;            // N*NBLK floats = 4 KB

    const int N = in_sizes[1];             // z_alpha is (N,1)
    dim3 grid(NBLK, N), block(TPB);
    k_partials<<<grid, block, 0, stream>>>(x, za, P);
    k_apply   <<<grid, block, 0, stream>>>(x, za, lt, lr, lk, P, out);
}